// Round 6
// baseline (460.466 us; speedup 1.0000x reference)
//
#include <hip/hip_runtime.h>
#include <math.h>

#define Bsz 128
#define Tsz 256
#define Isz 256
#define Hsz 256
#define Lsz 4
#define Ssz 3
#define Mrows (Bsz*Tsz)   // 32768

using f16x8 = __attribute__((ext_vector_type(8))) _Float16;
using f32x4 = __attribute__((ext_vector_type(4))) float;

#define LOG2E 1.44269504f

// ---------------- fp32 -> fp16 convert, 3 segments in one launch ----------------
__global__ __launch_bounds__(256) void f32_to_f16_3(
    const float* __restrict__ s0, _Float16* __restrict__ d0, int n0,
    const float* __restrict__ s1, _Float16* __restrict__ d1, int n1,
    const float* __restrict__ s2, _Float16* __restrict__ d2, int n2)
{
  int idx = blockIdx.x * 256 + threadIdx.x;
  const float* s; _Float16* d;
  if (idx < n0)           { s = s0; d = d0; }
  else if (idx < n0 + n1) { idx -= n0; s = s1; d = d1; }
  else                    { idx -= n0 + n1; if (idx >= n2) return; s = s2; d = d2; }
  const float4 v0 = *(const float4*)(s + (size_t)idx * 8);
  const float4 v1 = *(const float4*)(s + (size_t)idx * 8 + 4);
  _Float16 h[8];
  h[0] = (_Float16)v0.x; h[1] = (_Float16)v0.y;
  h[2] = (_Float16)v0.z; h[3] = (_Float16)v0.w;
  h[4] = (_Float16)v1.x; h[5] = (_Float16)v1.y;
  h[6] = (_Float16)v1.z; h[7] = (_Float16)v1.w;
  *(uint4*)(d + (size_t)idx * 8) = *(uint4*)h;
}

// ---------------- weight-stationary fused GRU-layer GEMM + fused ep ----------------
// Structure as R5 (proven): W frags register-stationary, A streamed in 32-row
// chunks through a 3-buffer LDS ring (global_load_lds, counted vmcnt(12)).
// NEW: when layer_ep >= 0, also computes the 7 per-row dots (4 w_lw + 3 w_sel)
// of the INPUT matrix A (= h_{layer_ep}) from the staged chunk:
//   block y covers k-planes [y*8, y*8+8) (64 cols); lane = (row=lane>>1,
//   half=lane&1) reads 8 cols, 56 mix-FMAs vs f16 reg weights, shfl_xor(1)
//   folds the plane pair, LDS partial tile PS, cross-wave reduce + atomicAdd.
// The atomic issues after the per-chunk wait point, so vmcnt(12) still always
// drains stage(t+1) (>=12 newer ops exist). e/p must be zeroed beforehand.
__global__ __launch_bounds__(256, 2) void gemm_gru_f16(
    const _Float16* __restrict__ Abase, size_t a_cur_stride,
    const _Float16* __restrict__ Wbase, size_t w_cur_stride,
    const float* __restrict__ bi_g, size_t bi_stride,
    const float* __restrict__ bh_g, size_t bh_stride,
    _Float16* __restrict__ Hout,
    const float* __restrict__ w_lw, const float* __restrict__ w_sel,
    float* __restrict__ e_out, float* __restrict__ p_out, int layer_ep)
{
  // 3 x 16 KB ring: 32 planes (pk) x 32 rows x 16B each.
  __shared__ _Float16 AhS[3][8192];
  __shared__ float PS[2][4][32][7];    // ep partials, double-buffered (7 KB)

  const int tid  = threadIdx.x;
  const int cu   = blockIdx.z;
  const int n0   = blockIdx.y * 64;
  const int rmb  = blockIdx.x * 512;       // this block's M range: 512 rows

  const _Float16* A = Abase + (size_t)cu * a_cur_stride;
  const _Float16* W = Wbase + (size_t)cu * w_cur_stride;
  const float* bi = bi_g + (size_t)cu * bi_stride;
  const float* bh = bh_g + (size_t)cu * bh_stride;

  const int lane = tid & 63;
  const int wv   = tid >> 6;       // wave id 0..3
  const int q    = lane >> 4;      // k-sub within frag (0..3)
  const int c    = lane & 15;      // row (A) / col (W,D) within frag

  // ---- load stationary W frags
  const int ncol = n0 + wv * 16 + c;
  f16x8 wf[3][8];
  #pragma unroll
  for (int s = 0; s < 3; s++)
    #pragma unroll
    for (int k0 = 0; k0 < 8; k0++)
      wf[s][k0] = *(const f16x8*)(W + (size_t)(s * 256 + ncol) * 256 + k0 * 32 + q * 8);
  #pragma unroll
  for (int s = 0; s < 3; s++)
    #pragma unroll
    for (int k0 = 0; k0 < 8; k0++)
      asm volatile("" : "+v"(wf[s][k0]));

  // ---- gating constants (biases folded into exp2 args)
  const float c0  = -LOG2E * (bi[ncol] + bh[ncol]);
  const float c1  =  LOG2E * (bi[256 + ncol] + bh[256 + ncol]);
  const float c3  = 2.f * LOG2E * bi[512 + ncol];
  const float bhn = bh[512 + ncol];

  // ---- ep setup: lane covers 8 cols of one row of the staged A chunk
  const int eprow = lane >> 1;                                // 0..31
  const int eppl  = blockIdx.y * 8 + wv * 2 + (lane & 1);     // plane 0..31
  f16x8 wep[7];
  if (layer_ep >= 0) {
    #pragma unroll
    for (int j = 0; j < 7; j++) {
      const float* wsrc = (j < 4) ? (w_lw + j * 256 + eppl * 8)
                                  : (w_sel + (size_t)(j - 4) * 512 + eppl * 8);
      const float4 wa = *(const float4*)wsrc;
      const float4 wb = *(const float4*)(wsrc + 4);
      f16x8 wv8;
      wv8[0] = (_Float16)wa.x; wv8[1] = (_Float16)wa.y;
      wv8[2] = (_Float16)wa.z; wv8[3] = (_Float16)wa.w;
      wv8[4] = (_Float16)wb.x; wv8[5] = (_Float16)wb.y;
      wv8[6] = (_Float16)wb.z; wv8[7] = (_Float16)wb.w;
      wep[j] = wv8;
    }
  }

  f32x4 acc[3][2];

  // ---- stage chunk (32 rows x 256 K): 16 x 1KB wave-instrs, 4/wave.
  auto stage = [&](int buf, int ch) {
    const int rm = rmb + ch * 32;
    #pragma unroll
    for (int i = 0; i < 4; i++) {
      const int p0 = 8 * wv + 2 * i;                 // base plane (uniform)
      const int pk = p0 + (lane >> 5);               // this lane's plane
      const _Float16* src = A + (size_t)(rm + (lane & 31)) * 256 + pk * 8;
      __builtin_amdgcn_global_load_lds(
          (const __attribute__((address_space(1))) void*)src,
          (__attribute__((address_space(3))) void*)&AhS[buf][p0 * 256],
          16, 0, 0);
    }
  };

  // ---- compute + gating + ep-partials for one chunk
  auto compute_chunk = [&](int buf, int ch) {
    const int rm = rmb + ch * 32;
    #pragma unroll
    for (int s = 0; s < 3; s++)
      #pragma unroll
      for (int mi = 0; mi < 2; mi++)
        acc[s][mi] = (f32x4)0.f;
    #pragma unroll
    for (int k0 = 0; k0 < 8; k0++) {
      const f16x8 a0 = *(const f16x8*)&AhS[buf][(k0 * 4 + q) * 256 + c * 8];
      const f16x8 a1 = *(const f16x8*)&AhS[buf][(k0 * 4 + q) * 256 + 128 + c * 8];
      #pragma unroll
      for (int s = 0; s < 3; s++) {
        acc[s][0] = __builtin_amdgcn_mfma_f32_16x16x32_f16(a0, wf[s][k0], acc[s][0], 0, 0, 0);
        acc[s][1] = __builtin_amdgcn_mfma_f32_16x16x32_f16(a1, wf[s][k0], acc[s][1], 0, 0, 0);
      }
    }
    // ---- ep partials from the staged A chunk (input h of this layer's gemm)
    if (layer_ep >= 0) {
      const f16x8 hv8 = *(const f16x8*)&AhS[buf][eppl * 256 + eprow * 8];
      float pacc[7];
      #pragma unroll
      for (int j = 0; j < 7; j++) {
        float a = 0.f;
        #pragma unroll
        for (int k = 0; k < 8; k++)
          a = fmaf((float)hv8[k], (float)wep[j][k], a);   // v_fma_mix
        pacc[j] = a + __shfl_xor(a, 1);                    // fold plane pair
      }
      if ((lane & 1) == 0) {
        #pragma unroll
        for (int j = 0; j < 7; j++) PS[ch & 1][wv][eprow][j] = pacc[j];
      }
    }
    // ---- gating epilogue
    #pragma unroll
    for (int mi = 0; mi < 2; mi++) {
      #pragma unroll
      for (int reg = 0; reg < 4; reg++) {
        const float ar = acc[0][mi][reg];
        const float az = acc[1][mi][reg];
        const float an = acc[2][mi][reg];
        const float e0 = __builtin_amdgcn_exp2f(fmaf(-LOG2E, ar, c0));
        const float r  = __builtin_amdgcn_rcpf(1.f + e0);
        const float e1 = __builtin_amdgcn_exp2f(fmaf(LOG2E, az, c1));
        const float tt = fmaf(r, bhn, an);
        const float a2 = fminf(fmaf(2.f * LOG2E, tt, c3), 120.f);
        const float e2 = __builtin_amdgcn_exp2f(a2);
        const float out = (e2 - 1.f) *
            __builtin_amdgcn_rcpf((1.f + e1) * (1.f + e2));
        const size_t row = (size_t)cu * Mrows + rm + mi * 16 + q * 4 + reg;
        Hout[row * 256 + ncol] = (_Float16)out;
      }
    }
  };

  // ---- per-chunk ep reduce + atomic (after barrier; PS[pb] complete)
  auto ep_accum = [&](int pb, int ch) {
    if (layer_ep < 0) return;
    if (tid < 224) {
      const int r = tid / 7, j = tid - r * 7;
      const float v = PS[pb][0][r][j] + PS[pb][1][r][j]
                    + PS[pb][2][r][j] + PS[pb][3][r][j];
      const int m  = rmb + ch * 32 + r;
      const int bb = m >> 8, ttim = m & 255;
      const size_t base = ((size_t)cu * Tsz + ttim) * Bsz + bb;
      if (j < 4) atomicAdd(&e_out[base * 16 + layer_ep * 4 + j], v);
      else       atomicAdd(&p_out[base * 12 + layer_ep * 3 + (j - 4)], v);
    }
  };

  // ---- prologue: 2 chunks in flight, drain chunk 0 (also drains wf/wep loads)
  stage(0, 0);
  stage(1, 1);
  asm volatile("s_waitcnt vmcnt(4)" ::: "memory");
  __builtin_amdgcn_s_barrier();

  // ---- main loop: {stage(t+2) || compute(t)}, one barrier/chunk.
  int bc = 0;
  for (int t = 0; t < 14; ++t) {
    int bs = bc + 2; if (bs >= 3) bs -= 3;
    stage(bs, t + 2);
    compute_chunk(bc, t);
    asm volatile("s_waitcnt vmcnt(12) lgkmcnt(0)" ::: "memory");
    __builtin_amdgcn_s_barrier();
    ep_accum(t & 1, t);
    bc = (bc + 1 == 3) ? 0 : bc + 1;
  }
  compute_chunk(bc, 14);                 // bc = 2; writes PS[0]
  asm volatile("s_waitcnt vmcnt(0) lgkmcnt(0)" ::: "memory");
  __builtin_amdgcn_s_barrier();
  ep_accum(0, 14);
  compute_chunk(0, 15);                  // writes PS[1]
  asm volatile("s_waitcnt lgkmcnt(0)" ::: "memory");
  __builtin_amdgcn_s_barrier();
  ep_accum(1, 15);
}

// ---------------- per-layer dot products (e, p) — used for layer 3 only ----------------
__global__ __launch_bounds__(256) void ep_tile(
    const _Float16* __restrict__ Hh,
    const float* __restrict__ w_lw, const float* __restrict__ w_sel, int layer,
    float* __restrict__ e, float* __restrict__ p)
{
  __shared__ _Float16 hs[64 * 264];   // 33 KB, padded stride
  __shared__ float wc[7][256];        // 7 KB
  __shared__ float ps[4][64][8];      // 8 KB partials
  const int tid = threadIdx.x;
  const size_t mg0 = (size_t)blockIdx.x * 64;

  #pragma unroll
  for (int i = 0; i < 8; i++) {
    const int ci = tid + i * 256;
    const int row = ci >> 5, kc = ci & 31;
    *(uint4*)&hs[row * 264 + kc * 8] =
        *(const uint4*)(Hh + (mg0 + row) * 256 + kc * 8);
  }
  #pragma unroll
  for (int j = 0; j < 7; j++)
    wc[j][tid] = (j < 4) ? w_lw[j * 256 + tid] : w_sel[(j - 4) * 512 + tid];
  __syncthreads();

  const int r = tid & 63, pp = tid >> 6;
  float acc[7] = {0.f, 0.f, 0.f, 0.f, 0.f, 0.f, 0.f};
  #pragma unroll
  for (int i = 0; i < 8; i++) {
    union { uint4 u; _Float16 h[8]; } hv;
    hv.u = *(uint4*)&hs[r * 264 + pp * 64 + i * 8];
    float hf[8];
    #pragma unroll
    for (int k = 0; k < 8; k++) hf[k] = (float)hv.h[k];
    #pragma unroll
    for (int j = 0; j < 7; j++) {
      const float4 w0 = *(const float4*)&wc[j][pp * 64 + i * 8];
      const float4 w1 = *(const float4*)&wc[j][pp * 64 + i * 8 + 4];
      acc[j] += hf[0] * w0.x + hf[1] * w0.y + hf[2] * w0.z + hf[3] * w0.w
              + hf[4] * w1.x + hf[5] * w1.y + hf[6] * w1.z + hf[7] * w1.w;
    }
  }
  #pragma unroll
  for (int j = 0; j < 7; j++) ps[pp][r][j] = acc[j];
  __syncthreads();

  if (tid < 64) {
    float d[7];
    #pragma unroll
    for (int j = 0; j < 7; j++)
      d[j] = ps[0][tid][j] + ps[1][tid][j] + ps[2][tid][j] + ps[3][tid][j];
    const size_t mg = mg0 + tid;
    const int cc = (int)(mg >> 15);
    const int m  = (int)(mg & 32767);
    const int b = m >> 8, t = m & 255;
    const size_t base = ((size_t)cc * Tsz + t) * Bsz + b;
    #pragma unroll
    for (int j = 0; j < 4; j++) e[base * 16 + layer * 4 + j] = d[j];
    #pragma unroll
    for (int j = 0; j < 3; j++) p[base * 12 + layer * 3 + j] = d[4 + j];
  }
}

// ---------------- softmax-attention + batch-reduced selector scores ----------------
__global__ __launch_bounds__(128) void attn_finish(
    const float* __restrict__ e, const float* __restrict__ p,
    const float* __restrict__ hidden, const float* __restrict__ b_lw,
    float* __restrict__ score_h)
{
  const int t = blockIdx.x, cc = blockIdx.y;
  const int b = threadIdx.x;
  const float* eb = e + ((size_t)(cc * Tsz + t) * Bsz + b) * 16;
  const float* pb = p + ((size_t)(cc * Tsz + t) * Bsz + b) * 12;
  const float* hb = hidden + b * 16;
  const float bl0 = b_lw[0], bl1 = b_lw[1], bl2 = b_lw[2], bl3 = b_lw[3];
  float attn[4];
  #pragma unroll
  for (int i = 0; i < 4; i++) {
    attn[i] = hb[i * 4 + 0] * (eb[i * 4 + 0] + bl0)
            + hb[i * 4 + 1] * (eb[i * 4 + 1] + bl1)
            + hb[i * 4 + 2] * (eb[i * 4 + 2] + bl2)
            + hb[i * 4 + 3] * (eb[i * 4 + 3] + bl3);
  }
  const float mx = fmaxf(fmaxf(attn[0], attn[1]), fmaxf(attn[2], attn[3]));
  float ex[4], sum = 0.f;
  #pragma unroll
  for (int i = 0; i < 4; i++) { ex[i] = expf(attn[i] - mx); sum += ex[i]; }
  const float inv = 1.f / sum;
  float sc[3];
  #pragma unroll
  for (int s = 0; s < 3; s++) {
    float v = 0.f;
    #pragma unroll
    for (int i = 0; i < 4; i++) v += ex[i] * pb[i * 3 + s];
    sc[s] = v * inv;
  }
  #pragma unroll
  for (int off = 32; off; off >>= 1)
    #pragma unroll
    for (int s = 0; s < 3; s++) sc[s] += __shfl_xor(sc[s], off);
  __shared__ float red[2][3];
  const int wv = threadIdx.x >> 6, ln = threadIdx.x & 63;
  if (ln == 0) { red[wv][0] = sc[0]; red[wv][1] = sc[1]; red[wv][2] = sc[2]; }
  __syncthreads();
  if (threadIdx.x == 0) {
    #pragma unroll
    for (int s = 0; s < 3; s++)
      score_h[((size_t)cc * Tsz + t) * 3 + s] = red[0][s] + red[1][s];
  }
}

// ---------------- xs[t,s] ----------------
__global__ __launch_bounds__(256) void xs_kernel(
    const float* __restrict__ x, const float* __restrict__ w_sel,
    const float* __restrict__ b_sel, float* __restrict__ xs)
{
  const int t = blockIdx.x, k = threadIdx.x;
  float s = 0.f;
  for (int b = 0; b < Bsz; b++) s += x[((size_t)b * Tsz + t) * Isz + k];
  float pr[3];
  #pragma unroll
  for (int qq = 0; qq < 3; qq++) pr[qq] = s * w_sel[qq * (Hsz + Isz) + Hsz + k];
  #pragma unroll
  for (int off = 32; off; off >>= 1)
    #pragma unroll
    for (int qq = 0; qq < 3; qq++) pr[qq] += __shfl_xor(pr[qq], off);
  __shared__ float red[4][3];
  const int wv = k >> 6, ln = k & 63;
  if (ln == 0) { red[wv][0] = pr[0]; red[wv][1] = pr[1]; red[wv][2] = pr[2]; }
  __syncthreads();
  if (k == 0) {
    #pragma unroll
    for (int qq = 0; qq < 3; qq++)
      xs[t * 3 + qq] = red[0][qq] + red[1][qq] + red[2][qq] + red[3][qq]
                      + (float)Bsz * b_sel[qq];
  }
}

// ---------------- serial selector chain ----------------
__global__ __launch_bounds__(256) void select_kernel(
    const float* __restrict__ score_h, const float* __restrict__ xs,
    int* __restrict__ cur)
{
  __shared__ int f[Tsz][3];
  const int tid = threadIdx.x;
  for (int u = tid; u < (Tsz - 1) * 3; u += 256) {
    const int t = 1 + u / 3, cc = u % 3;
    const float* sh = score_h + ((size_t)cc * Tsz + (t - 1)) * 3;
    const float* xr = xs + t * 3;
    const float v0 = sh[0] + xr[0];
    const float v1 = sh[1] + xr[1];
    const float v2 = sh[2] + xr[2];
    int best = 0; float bv = v0;
    if (v1 > bv) { bv = v1; best = 1; }
    if (v2 > bv) { bv = v2; best = 2; }
    f[t][cc] = best;
  }
  __syncthreads();
  if (tid == 0) {
    int cc = 0; cur[0] = 0;
    for (int t = 1; t < Tsz; t++) { cc = f[t][cc]; cur[t] = cc; }
  }
}

// ---------------- gather outputs (fp16 h -> fp32 out) ----------------
__global__ __launch_bounds__(256) void gather_out(
    const _Float16* __restrict__ Hh, const int* __restrict__ cur,
    float* __restrict__ out)
{
  const size_t idx = ((size_t)blockIdx.x * 256 + threadIdx.x) * 4;
  const size_t BTH = (size_t)Bsz * Tsz * Hsz;
  int b, t, h;
  if (idx < BTH) {
    b = (int)(idx >> 16);
    const int rem = (int)(idx & 65535);
    t = rem >> 8; h = rem & 255;
  } else {
    const size_t r2 = idx - BTH;
    b = (int)(r2 >> 8); h = (int)(r2 & 255); t = Tsz - 1;
  }
  const int cc = cur[t];
  const size_t g = (((size_t)cc * Mrows + (size_t)b * Tsz + t) * Hsz + h);
  union { ushort4 u; _Float16 hv[4]; } cv;
  cv.u = *(const ushort4*)(Hh + g);
  float4 v;
  v.x = (float)cv.hv[0]; v.y = (float)cv.hv[1];
  v.z = (float)cv.hv[2]; v.w = (float)cv.hv[3];
  *(float4*)(out + idx) = v;
}

extern "C" void kernel_launch(void* const* d_in, const int* in_sizes, int n_in,
                              void* d_out, int out_size, void* d_ws, size_t ws_size,
                              hipStream_t stream) {
  const float* x      = (const float*)d_in[0];
  const float* hidden = (const float*)d_in[1];
  const float* w_ih0  = (const float*)d_in[2];
  const float* b_ih0  = (const float*)d_in[3];
  const float* b_hh0  = (const float*)d_in[4];
  const float* w_ih   = (const float*)d_in[5];
  const float* b_ih   = (const float*)d_in[6];
  const float* b_hh   = (const float*)d_in[7];
  const float* w_lw   = (const float*)d_in[8];
  const float* b_lw   = (const float*)d_in[9];
  const float* w_sel  = (const float*)d_in[10];
  const float* b_sel  = (const float*)d_in[11];
  float* out = (float*)d_out;

  char* w = (char*)d_ws;
  const size_t HN = (size_t)3 * Mrows * 256;       // 25.2M
  const size_t XN = (size_t)Bsz * Tsz * Isz;       // 8.39M
  const size_t W0N = (size_t)3 * 768 * 256;        // 589824
  const size_t WLN = (size_t)3 * 3 * 768 * 256;    // 1769472
  _Float16* HA  = (_Float16*)w; w += HN * 2;
  _Float16* HB  = (_Float16*)w; w += HN * 2;
  _Float16* xh  = (_Float16*)w; w += XN * 2;
  _Float16* Wh0 = (_Float16*)w; w += W0N * 2;
  _Float16* WhL = (_Float16*)w; w += WLN * 2;
  float* e       = (float*)w; w += (size_t)3 * Tsz * Bsz * 16 * 4;
  float* p       = (float*)w; w += (size_t)3 * Tsz * Bsz * 12 * 4;
  float* score_h = (float*)w; w += (size_t)3 * Tsz * 3 * 4;
  float* xsb     = (float*)w; w += (size_t)Tsz * 3 * 4;
  int*   curb    = (int*)w;   w += (size_t)Tsz * 4;

  // zero e/p (fused-ep atomics accumulate into them)
  hipMemsetAsync(e, 0, (size_t)3 * Tsz * Bsz * 16 * 4, stream);
  hipMemsetAsync(p, 0, (size_t)3 * Tsz * Bsz * 12 * 4, stream);

  // fp32 -> fp16 conversions (one launch, 3 segments; all counts /8 and %256==0)
  f32_to_f16_3<<<5248, 256, 0, stream>>>(
      x, xh, (int)(XN / 8),
      w_ih0, Wh0, (int)(W0N / 8),
      w_ih, WhL, (int)(WLN / 8));

  // weight-stationary GEMM grid: (mseg, n-tile, cur)
  dim3 ggrid(64, 4, 3);

  // layer 0: A = xh (shared across cur), no ep
  gemm_gru_f16<<<ggrid, 256, 0, stream>>>(
      xh, (size_t)0, Wh0, (size_t)768 * 256,
      b_ih0, (size_t)768, b_hh0, (size_t)768, HA,
      nullptr, nullptr, nullptr, nullptr, -1);

  const size_t wcur = (size_t)3 * 768 * 256;
  const size_t bst  = (size_t)3 * 768;
  _Float16* ping = HA; _Float16* pong = HB;
  for (int l = 1; l < 4; l++) {
    // gemm(l) computes h_l from A=h_{l-1}; fused ep for layer l-1
    gemm_gru_f16<<<ggrid, 256, 0, stream>>>(
        ping, (size_t)Mrows * 256,
        WhL + (size_t)(l - 1) * 768 * 256, wcur,
        b_ih + (size_t)(l - 1) * 768, bst,
        b_hh + (size_t)(l - 1) * 768, bst, pong,
        w_lw, w_sel, e, p, l - 1);
    _Float16* t1 = ping; ping = pong; pong = t1;
  }
  // ep for layer 3 (no following gemm)
  ep_tile<<<(3 * Mrows) / 64, 256, 0, stream>>>(ping, w_lw, w_sel, 3, e, p);

  attn_finish<<<dim3(Tsz, 3), 128, 0, stream>>>(e, p, hidden, b_lw, score_h);
  xs_kernel<<<Tsz, 256, 0, stream>>>(x, w_sel, b_sel, xsb);
  select_kernel<<<1, 256, 0, stream>>>(score_h, xsb, curb);
  gather_out<<<8224, 256, 0, stream>>>(ping, curb, out);
}

// Round 7
// 410.207 us; speedup vs baseline: 1.1225x; 1.1225x over previous
//
#include <hip/hip_runtime.h>
#include <math.h>

#define Bsz 128
#define Tsz 256
#define Isz 256
#define Hsz 256
#define Lsz 4
#define Ssz 3
#define Mrows (Bsz*Tsz)   // 32768

using f16x8 = __attribute__((ext_vector_type(8))) _Float16;
using f32x4 = __attribute__((ext_vector_type(4))) float;

#define LOG2E 1.44269504f

// ---------------- fp32 -> fp16 convert, 3 segments in one launch ----------------
__global__ __launch_bounds__(256) void f32_to_f16_3(
    const float* __restrict__ s0, _Float16* __restrict__ d0, int n0,
    const float* __restrict__ s1, _Float16* __restrict__ d1, int n1,
    const float* __restrict__ s2, _Float16* __restrict__ d2, int n2)
{
  int idx = blockIdx.x * 256 + threadIdx.x;
  const float* s; _Float16* d;
  if (idx < n0)           { s = s0; d = d0; }
  else if (idx < n0 + n1) { idx -= n0; s = s1; d = d1; }
  else                    { idx -= n0 + n1; if (idx >= n2) return; s = s2; d = d2; }
  const float4 v0 = *(const float4*)(s + (size_t)idx * 8);
  const float4 v1 = *(const float4*)(s + (size_t)idx * 8 + 4);
  _Float16 h[8];
  h[0] = (_Float16)v0.x; h[1] = (_Float16)v0.y;
  h[2] = (_Float16)v0.z; h[3] = (_Float16)v0.w;
  h[4] = (_Float16)v1.x; h[5] = (_Float16)v1.y;
  h[6] = (_Float16)v1.z; h[7] = (_Float16)v1.w;
  *(uint4*)(d + (size_t)idx * 8) = *(uint4*)h;
}

// ---------------- weight-stationary fused GRU-layer GEMM, fp16 MFMA ----------------
// R5-proven structure (55.3 us/dispatch): W frags pinned in registers (96
// VGPR/lane), A streamed in 32-row chunks through a 3-buffer LDS ring via
// global_load_lds, 2-deep prefetch, ONE barrier + counted vmcnt(12)/chunk
// (12 = 4 stage + 8 stores in flight). Gating epilogue: 3 v_exp + 2 v_rcp
// per output, biases pre-folded into exp2 args.
__global__ __launch_bounds__(256, 2) void gemm_gru_f16(
    const _Float16* __restrict__ Abase, size_t a_cur_stride,
    const _Float16* __restrict__ Wbase, size_t w_cur_stride,
    const float* __restrict__ bi_g, size_t bi_stride,
    const float* __restrict__ bh_g, size_t bh_stride,
    _Float16* __restrict__ Hout)
{
  // 3 x 16 KB ring: 32 planes (pk = k0*4+q) x 32 rows x 16B each.
  __shared__ _Float16 AhS[3][8192];

  const int tid  = threadIdx.x;
  const int cu   = blockIdx.z;
  const int n0   = blockIdx.y * 64;
  const int rmb  = blockIdx.x * 512;       // this block's M range: 512 rows

  const _Float16* A = Abase + (size_t)cu * a_cur_stride;
  const _Float16* W = Wbase + (size_t)cu * w_cur_stride;
  const float* bi = bi_g + (size_t)cu * bi_stride;
  const float* bh = bh_g + (size_t)cu * bh_stride;

  const int lane = tid & 63;
  const int wv   = tid >> 6;       // wave id 0..3
  const int q    = lane >> 4;      // k-sub within frag (0..3)
  const int c    = lane & 15;      // row (A) / col (W,D) within frag

  // ---- load stationary W frags: wf[slab][k0], lane(q,c) = W[s*256+ncol][k0*32+q*8..+7]
  const int ncol = n0 + wv * 16 + c;
  f16x8 wf[3][8];
  #pragma unroll
  for (int s = 0; s < 3; s++)
    #pragma unroll
    for (int k0 = 0; k0 < 8; k0++)
      wf[s][k0] = *(const f16x8*)(W + (size_t)(s * 256 + ncol) * 256 + k0 * 32 + q * 8);
  // pin: force wf to live in VGPRs once; defeats rematerialization into the loop
  #pragma unroll
  for (int s = 0; s < 3; s++)
    #pragma unroll
    for (int k0 = 0; k0 < 8; k0++)
      asm volatile("" : "+v"(wf[s][k0]));

  // ---- biases folded into exp2 arguments (per-lane constants)
  const float c0  = -LOG2E * (bi[ncol] + bh[ncol]);
  const float c1  =  LOG2E * (bi[256 + ncol] + bh[256 + ncol]);
  const float c3  = 2.f * LOG2E * bi[512 + ncol];
  const float bhn = bh[512 + ncol];

  f32x4 acc[3][2];

  // ---- stage chunk (32 rows x 256 K) into buf: 16 x 1KB wave-instrs, 4/wave.
  auto stage = [&](int buf, int ch) {
    const int rm = rmb + ch * 32;
    #pragma unroll
    for (int i = 0; i < 4; i++) {
      const int p0 = 8 * wv + 2 * i;                 // base plane (uniform)
      const int pk = p0 + (lane >> 5);               // this lane's plane
      const _Float16* src = A + (size_t)(rm + (lane & 31)) * 256 + pk * 8;
      __builtin_amdgcn_global_load_lds(
          (const __attribute__((address_space(1))) void*)src,
          (__attribute__((address_space(3))) void*)&AhS[buf][p0 * 256],
          16, 0, 0);
    }
  };

  // ---- compute + fused gating epilogue for one chunk (8 outputs/lane)
  auto compute_chunk = [&](int buf, int ch) {
    const int rm = rmb + ch * 32;
    #pragma unroll
    for (int s = 0; s < 3; s++)
      #pragma unroll
      for (int mi = 0; mi < 2; mi++)
        acc[s][mi] = (f32x4)0.f;
    #pragma unroll
    for (int k0 = 0; k0 < 8; k0++) {
      const f16x8 a0 = *(const f16x8*)&AhS[buf][(k0 * 4 + q) * 256 + c * 8];
      const f16x8 a1 = *(const f16x8*)&AhS[buf][(k0 * 4 + q) * 256 + 128 + c * 8];
      #pragma unroll
      for (int s = 0; s < 3; s++) {
        acc[s][0] = __builtin_amdgcn_mfma_f32_16x16x32_f16(a0, wf[s][k0], acc[s][0], 0, 0, 0);
        acc[s][1] = __builtin_amdgcn_mfma_f32_16x16x32_f16(a1, wf[s][k0], acc[s][1], 0, 0, 0);
      }
    }
    #pragma unroll
    for (int mi = 0; mi < 2; mi++) {
      #pragma unroll
      for (int reg = 0; reg < 4; reg++) {
        const float ar = acc[0][mi][reg];
        const float az = acc[1][mi][reg];
        const float an = acc[2][mi][reg];
        const float e0 = __builtin_amdgcn_exp2f(fmaf(-LOG2E, ar, c0));
        const float r  = __builtin_amdgcn_rcpf(1.f + e0);
        const float e1 = __builtin_amdgcn_exp2f(fmaf(LOG2E, az, c1));
        const float tt = fmaf(r, bhn, an);
        const float a2 = fminf(fmaf(2.f * LOG2E, tt, c3), 120.f);
        const float e2 = __builtin_amdgcn_exp2f(a2);
        const float out = (e2 - 1.f) *
            __builtin_amdgcn_rcpf((1.f + e1) * (1.f + e2));
        const size_t row = (size_t)cu * Mrows + rm + mi * 16 + q * 4 + reg;
        Hout[row * 256 + ncol] = (_Float16)out;
      }
    }
  };

  // ---- prologue: 2 chunks in flight, drain chunk 0
  stage(0, 0);
  stage(1, 1);
  asm volatile("s_waitcnt vmcnt(4)" ::: "memory");
  __builtin_amdgcn_s_barrier();

  // ---- main loop: {stage(t+2) || compute(t)}, one barrier/chunk.
  int bc = 0;
  for (int t = 0; t < 14; ++t) {
    int bs = bc + 2; if (bs >= 3) bs -= 3;
    stage(bs, t + 2);
    compute_chunk(bc, t);
    asm volatile("s_waitcnt vmcnt(12)" ::: "memory");
    __builtin_amdgcn_s_barrier();
    bc = (bc + 1 == 3) ? 0 : bc + 1;
  }
  compute_chunk(bc, 14);                 // bc = 2 = 14%3
  asm volatile("s_waitcnt vmcnt(0)" ::: "memory");
  __builtin_amdgcn_s_barrier();
  bc = (bc + 1 == 3) ? 0 : bc + 1;       // = 0 = 15%3
  compute_chunk(bc, 15);
}

// ---------------- per-layer dot products (e, p), de-staged ----------------
// h is streamed once (no reuse) -> no LDS staging for h; each thread reads its
// own 64B row-quarter directly from global (L2/L3-hot). Only the 7x256 weight
// block is LDS-resident.
__global__ __launch_bounds__(256) void ep_tile(
    const _Float16* __restrict__ Hh,
    const float* __restrict__ w_lw, const float* __restrict__ w_sel, int layer,
    float* __restrict__ e, float* __restrict__ p)
{
  __shared__ float wc[7][256];        // 7 KB
  __shared__ float ps[4][64][8];      // 8 KB partials
  const int tid = threadIdx.x;
  const size_t mg0 = (size_t)blockIdx.x * 64;

  // stage weight block: rows 0-3 = w_lw, 4-6 = w_sel[:, 0:256]
  #pragma unroll
  for (int j = 0; j < 7; j++)
    wc[j][tid] = (j < 4) ? w_lw[j * 256 + tid] : w_sel[(j - 4) * 512 + tid];
  __syncthreads();

  const int r = tid & 63, pp = tid >> 6;
  const _Float16* hrow = Hh + (mg0 + r) * 256 + pp * 64;
  float acc[7] = {0.f, 0.f, 0.f, 0.f, 0.f, 0.f, 0.f};
  #pragma unroll
  for (int i = 0; i < 8; i++) {
    union { uint4 u; _Float16 h[8]; } hv;
    hv.u = *(const uint4*)(hrow + i * 8);
    float hf[8];
    #pragma unroll
    for (int k = 0; k < 8; k++) hf[k] = (float)hv.h[k];
    #pragma unroll
    for (int j = 0; j < 7; j++) {
      const float4 w0 = *(const float4*)&wc[j][pp * 64 + i * 8];
      const float4 w1 = *(const float4*)&wc[j][pp * 64 + i * 8 + 4];
      acc[j] += hf[0] * w0.x + hf[1] * w0.y + hf[2] * w0.z + hf[3] * w0.w
              + hf[4] * w1.x + hf[5] * w1.y + hf[6] * w1.z + hf[7] * w1.w;
    }
  }
  #pragma unroll
  for (int j = 0; j < 7; j++) ps[pp][r][j] = acc[j];
  __syncthreads();

  if (tid < 64) {
    float d[7];
    #pragma unroll
    for (int j = 0; j < 7; j++)
      d[j] = ps[0][tid][j] + ps[1][tid][j] + ps[2][tid][j] + ps[3][tid][j];
    const size_t mg = mg0 + tid;
    const int cc = (int)(mg >> 15);          // / Mrows
    const int m  = (int)(mg & 32767);
    const int b = m >> 8, t = m & 255;
    const size_t base = ((size_t)cc * Tsz + t) * Bsz + b;
    #pragma unroll
    for (int j = 0; j < 4; j++) e[base * 16 + layer * 4 + j] = d[j];
    #pragma unroll
    for (int j = 0; j < 3; j++) p[base * 12 + layer * 3 + j] = d[4 + j];
  }
}

// ---------------- softmax-attention + batch-reduced selector scores ----------------
__global__ __launch_bounds__(128) void attn_finish(
    const float* __restrict__ e, const float* __restrict__ p,
    const float* __restrict__ hidden, const float* __restrict__ b_lw,
    float* __restrict__ score_h)
{
  const int t = blockIdx.x, cc = blockIdx.y;
  const int b = threadIdx.x;
  const float* eb = e + ((size_t)(cc * Tsz + t) * Bsz + b) * 16;
  const float* pb = p + ((size_t)(cc * Tsz + t) * Bsz + b) * 12;
  const float* hb = hidden + b * 16;
  const float bl0 = b_lw[0], bl1 = b_lw[1], bl2 = b_lw[2], bl3 = b_lw[3];
  float attn[4];
  #pragma unroll
  for (int i = 0; i < 4; i++) {
    attn[i] = hb[i * 4 + 0] * (eb[i * 4 + 0] + bl0)
            + hb[i * 4 + 1] * (eb[i * 4 + 1] + bl1)
            + hb[i * 4 + 2] * (eb[i * 4 + 2] + bl2)
            + hb[i * 4 + 3] * (eb[i * 4 + 3] + bl3);
  }
  const float mx = fmaxf(fmaxf(attn[0], attn[1]), fmaxf(attn[2], attn[3]));
  float ex[4], sum = 0.f;
  #pragma unroll
  for (int i = 0; i < 4; i++) { ex[i] = expf(attn[i] - mx); sum += ex[i]; }
  const float inv = 1.f / sum;
  float sc[3];
  #pragma unroll
  for (int s = 0; s < 3; s++) {
    float v = 0.f;
    #pragma unroll
    for (int i = 0; i < 4; i++) v += ex[i] * pb[i * 3 + s];
    sc[s] = v * inv;
  }
  #pragma unroll
  for (int off = 32; off; off >>= 1)
    #pragma unroll
    for (int s = 0; s < 3; s++) sc[s] += __shfl_xor(sc[s], off);
  __shared__ float red[2][3];
  const int wv = threadIdx.x >> 6, ln = threadIdx.x & 63;
  if (ln == 0) { red[wv][0] = sc[0]; red[wv][1] = sc[1]; red[wv][2] = sc[2]; }
  __syncthreads();
  if (threadIdx.x == 0) {
    #pragma unroll
    for (int s = 0; s < 3; s++)
      score_h[((size_t)cc * Tsz + t) * 3 + s] = red[0][s] + red[1][s];
  }
}

// ---------------- xs[t,s] ----------------
__global__ __launch_bounds__(256) void xs_kernel(
    const float* __restrict__ x, const float* __restrict__ w_sel,
    const float* __restrict__ b_sel, float* __restrict__ xs)
{
  const int t = blockIdx.x, k = threadIdx.x;
  float s = 0.f;
  for (int b = 0; b < Bsz; b++) s += x[((size_t)b * Tsz + t) * Isz + k];
  float pr[3];
  #pragma unroll
  for (int qq = 0; qq < 3; qq++) pr[qq] = s * w_sel[qq * (Hsz + Isz) + Hsz + k];
  #pragma unroll
  for (int off = 32; off; off >>= 1)
    #pragma unroll
    for (int qq = 0; qq < 3; qq++) pr[qq] += __shfl_xor(pr[qq], off);
  __shared__ float red[4][3];
  const int wv = k >> 6, ln = k & 63;
  if (ln == 0) { red[wv][0] = pr[0]; red[wv][1] = pr[1]; red[wv][2] = pr[2]; }
  __syncthreads();
  if (k == 0) {
    #pragma unroll
    for (int qq = 0; qq < 3; qq++)
      xs[t * 3 + qq] = red[0][qq] + red[1][qq] + red[2][qq] + red[3][qq]
                      + (float)Bsz * b_sel[qq];
  }
}

// ---------------- serial selector chain ----------------
__global__ __launch_bounds__(256) void select_kernel(
    const float* __restrict__ score_h, const float* __restrict__ xs,
    int* __restrict__ cur)
{
  __shared__ int f[Tsz][3];
  const int tid = threadIdx.x;
  for (int u = tid; u < (Tsz - 1) * 3; u += 256) {
    const int t = 1 + u / 3, cc = u % 3;
    const float* sh = score_h + ((size_t)cc * Tsz + (t - 1)) * 3;
    const float* xr = xs + t * 3;
    const float v0 = sh[0] + xr[0];
    const float v1 = sh[1] + xr[1];
    const float v2 = sh[2] + xr[2];
    int best = 0; float bv = v0;
    if (v1 > bv) { bv = v1; best = 1; }
    if (v2 > bv) { bv = v2; best = 2; }
    f[t][cc] = best;
  }
  __syncthreads();
  if (tid == 0) {
    int cc = 0; cur[0] = 0;
    for (int t = 1; t < Tsz; t++) { cc = f[t][cc]; cur[t] = cc; }
  }
}

// ---------------- gather outputs (fp16 h -> fp32 out) ----------------
__global__ __launch_bounds__(256) void gather_out(
    const _Float16* __restrict__ Hh, const int* __restrict__ cur,
    float* __restrict__ out)
{
  const size_t idx = ((size_t)blockIdx.x * 256 + threadIdx.x) * 4;
  const size_t BTH = (size_t)Bsz * Tsz * Hsz;
  int b, t, h;
  if (idx < BTH) {
    b = (int)(idx >> 16);
    const int rem = (int)(idx & 65535);
    t = rem >> 8; h = rem & 255;
  } else {
    const size_t r2 = idx - BTH;
    b = (int)(r2 >> 8); h = (int)(r2 & 255); t = Tsz - 1;
  }
  const int cc = cur[t];
  const size_t g = (((size_t)cc * Mrows + (size_t)b * Tsz + t) * Hsz + h);
  union { ushort4 u; _Float16 hv[4]; } cv;
  cv.u = *(const ushort4*)(Hh + g);
  float4 v;
  v.x = (float)cv.hv[0]; v.y = (float)cv.hv[1];
  v.z = (float)cv.hv[2]; v.w = (float)cv.hv[3];
  *(float4*)(out + idx) = v;
}

extern "C" void kernel_launch(void* const* d_in, const int* in_sizes, int n_in,
                              void* d_out, int out_size, void* d_ws, size_t ws_size,
                              hipStream_t stream) {
  const float* x      = (const float*)d_in[0];
  const float* hidden = (const float*)d_in[1];
  const float* w_ih0  = (const float*)d_in[2];
  const float* b_ih0  = (const float*)d_in[3];
  const float* b_hh0  = (const float*)d_in[4];
  const float* w_ih   = (const float*)d_in[5];
  const float* b_ih   = (const float*)d_in[6];
  const float* b_hh   = (const float*)d_in[7];
  const float* w_lw   = (const float*)d_in[8];
  const float* b_lw   = (const float*)d_in[9];
  const float* w_sel  = (const float*)d_in[10];
  const float* b_sel  = (const float*)d_in[11];
  float* out = (float*)d_out;

  char* w = (char*)d_ws;
  const size_t HN = (size_t)3 * Mrows * 256;       // 25.2M
  const size_t XN = (size_t)Bsz * Tsz * Isz;       // 8.39M
  const size_t W0N = (size_t)3 * 768 * 256;        // 589824
  const size_t WLN = (size_t)3 * 3 * 768 * 256;    // 1769472
  _Float16* HA  = (_Float16*)w; w += HN * 2;
  _Float16* HB  = (_Float16*)w; w += HN * 2;
  _Float16* xh  = (_Float16*)w; w += XN * 2;
  _Float16* Wh0 = (_Float16*)w; w += W0N * 2;
  _Float16* WhL = (_Float16*)w; w += WLN * 2;
  float* e       = (float*)w; w += (size_t)3 * Tsz * Bsz * 16 * 4;
  float* p       = (float*)w; w += (size_t)3 * Tsz * Bsz * 12 * 4;
  float* score_h = (float*)w; w += (size_t)3 * Tsz * 3 * 4;
  float* xsb     = (float*)w; w += (size_t)Tsz * 3 * 4;
  int*   curb    = (int*)w;   w += (size_t)Tsz * 4;

  // fp32 -> fp16 conversions (one launch, 3 segments)
  f32_to_f16_3<<<5248, 256, 0, stream>>>(
      x, xh, (int)(XN / 8),
      w_ih0, Wh0, (int)(W0N / 8),
      w_ih, WhL, (int)(WLN / 8));

  // weight-stationary GEMM grid: (mseg, n-tile, cur)
  dim3 ggrid(64, 4, 3);

  // layer 0: A = xh (shared across cur)
  gemm_gru_f16<<<ggrid, 256, 0, stream>>>(
      xh, (size_t)0, Wh0, (size_t)768 * 256,
      b_ih0, (size_t)768, b_hh0, (size_t)768, HA);
  ep_tile<<<(3 * Mrows) / 64, 256, 0, stream>>>(HA, w_lw, w_sel, 0, e, p);

  const size_t wcur = (size_t)3 * 768 * 256;
  const size_t bst  = (size_t)3 * 768;
  _Float16* ping = HA; _Float16* pong = HB;
  for (int l = 1; l < 4; l++) {
    gemm_gru_f16<<<ggrid, 256, 0, stream>>>(
        ping, (size_t)Mrows * 256,
        WhL + (size_t)(l - 1) * 768 * 256, wcur,
        b_ih + (size_t)(l - 1) * 768, bst,
        b_hh + (size_t)(l - 1) * 768, bst, pong);
    ep_tile<<<(3 * Mrows) / 64, 256, 0, stream>>>(pong, w_lw, w_sel, l, e, p);
    _Float16* t1 = ping; ping = pong; pong = t1;
  }

  attn_finish<<<dim3(Tsz, 3), 128, 0, stream>>>(e, p, hidden, b_lw, score_h);
  xs_kernel<<<Tsz, 256, 0, stream>>>(x, w_sel, b_sel, xsb);
  select_kernel<<<1, 256, 0, stream>>>(score_h, xsb, curb);
  gather_out<<<8224, 256, 0, stream>>>(ping, curb, out);
}